// Round 1
// baseline (65.524 us; speedup 1.0000x reference)
//
#include <hip/hip_runtime.h>
#include <math.h>

// Problem constants (from reference)
#define B_N   32768
#define P_N   128
#define X_N   30
#define Y_N   30
#define F_N   6
#define CELLS (X_N * Y_N)      // 900
#define INV_T 1000.0f          // 1 / 0.001

// ---------------------------------------------------------------------------
// Kernel 1: build V[cell] = sum_p softmax_p(s/T) * s,
//           s[p,cell] = dot(succ_feats[p, cell, :], w)
// succ_feats layout: [P, X, Y, F] -> sf[p*5400 + cell*6 + f]
// One wave (64 lanes) per cell; lane handles p = lane and p = lane + 64.
// ---------------------------------------------------------------------------
__global__ __launch_bounds__(64) void build_table_kernel(
    const float* __restrict__ sf, const float* __restrict__ w,
    float* __restrict__ V)
{
    const int cell = blockIdx.x;      // 0..899
    const int lane = threadIdx.x;     // 0..63

    float wv[F_N];
#pragma unroll
    for (int f = 0; f < F_N; ++f) wv[f] = w[f];

    const float* b0 = sf + (size_t)lane        * (CELLS * F_N) + (size_t)cell * F_N;
    const float* b1 = sf + (size_t)(lane + 64) * (CELLS * F_N) + (size_t)cell * F_N;

    float d0 = 0.f, d1 = 0.f;
#pragma unroll
    for (int f = 0; f < F_N; ++f) {
        d0 = fmaf(b0[f], wv[f], d0);
        d1 = fmaf(b1[f], wv[f], d1);
    }

    // wave-wide max over all 128 values
    float m = fmaxf(d0, d1);
#pragma unroll
    for (int off = 32; off >= 1; off >>= 1)
        m = fmaxf(m, __shfl_xor(m, off, 64));

    float e0 = __expf((d0 - m) * INV_T);
    float e1 = __expf((d1 - m) * INV_T);
    float num = e0 * d0 + e1 * d1;
    float den = e0 + e1;
#pragma unroll
    for (int off = 32; off >= 1; off >>= 1) {
        num += __shfl_xor(num, off, 64);
        den += __shfl_xor(den, off, 64);
    }

    if (lane == 0) V[cell] = num / den;
}

// ---------------------------------------------------------------------------
// Kernel 2: per-b epilogue.
// phi layout: [B, 2, 10] -> 20 floats per b, 16B-aligned (80B stride).
//   t*10 + {0..5}=feats, 6=x_ss, 7=y_ss, 8=x_es, 9=y_es
// out layout: [B, 2, 1] -> out[2b], out[2b+1]
// ---------------------------------------------------------------------------
__global__ __launch_bounds__(256) void finalize_kernel(
    const float* __restrict__ phi, const float* __restrict__ w,
    const float* __restrict__ V, float* __restrict__ out)
{
    __shared__ float Vs[CELLS];
    for (int i = threadIdx.x; i < CELLS; i += blockDim.x)
        Vs[i] = V[i];
    __syncthreads();

    const int b = blockIdx.x * blockDim.x + threadIdx.x;
    if (b >= B_N) return;

    const float w0 = w[0], w1 = w[1], w2 = w[2], w3 = w[3], w4 = w[4], w5 = w[5];

    const float4* p4 = (const float4*)(phi + (size_t)b * 20);
    float4 c0 = p4[0];  // t0: f0 f1 f2 f3
    float4 c1 = p4[1];  // t0: f4 f5 x_ss y_ss
    float4 c2 = p4[2];  // t0: x_es y_es | t1: f0 f1
    float4 c3 = p4[3];  // t1: f2 f3 f4 f5
    float4 c4 = p4[4];  // t1: x_ss y_ss x_es y_es

    float pr0 = c0.x*w0 + c0.y*w1 + c0.z*w2 + c0.w*w3 + c1.x*w4 + c1.y*w5;
    float pr1 = c2.z*w0 + c2.w*w1 + c3.x*w2 + c3.y*w3 + c3.z*w4 + c3.w*w5;

    int iss0 = (int)c1.z * Y_N + (int)c1.w;
    int ies0 = (int)c2.x * Y_N + (int)c2.y;
    int iss1 = (int)c4.x * Y_N + (int)c4.y;
    int ies1 = (int)c4.z * Y_N + (int)c4.w;

    float d0 = pr0 + Vs[ies0] - Vs[iss0];
    float d1 = pr1 + Vs[ies1] - Vs[iss1];

    float x = d0 - d1;
    float s0 = 1.0f / (1.0f + expf(-x));
    float s1 = 1.0f / (1.0f + expf(x));

    float2* o2 = (float2*)(out + (size_t)b * 2);
    *o2 = make_float2(s0, s1);
}

// ---------------------------------------------------------------------------
extern "C" void kernel_launch(void* const* d_in, const int* in_sizes, int n_in,
                              void* d_out, int out_size, void* d_ws, size_t ws_size,
                              hipStream_t stream) {
    const float* phi = (const float*)d_in[0];   // (B, 2, 10)
    const float* sf  = (const float*)d_in[1];   // (P, X, Y, F)
    const float* w   = (const float*)d_in[2];   // (F,)
    float* out = (float*)d_out;                 // (B, 2, 1)
    float* V   = (float*)d_ws;                  // 900 floats

    build_table_kernel<<<CELLS, 64, 0, stream>>>(sf, w, V);
    finalize_kernel<<<(B_N + 255) / 256, 256, 0, stream>>>(phi, w, V, out);
}